// Round 1
// baseline (185.270 us; speedup 1.0000x reference)
//
#include <hip/hip_runtime.h>
#include <hip/hip_bf16.h>
#include <stdint.h>
#include <stddef.h>

// Problem constants
#define BT_TOK   32768      // B*T
#define IN_DIM   512
#define OUT_DIM  512
#define QDIM     32
#define GV       64         // G*V
#define NG       8
#define NV       8
#define VD       64
#define EPS_G    1e-10f

// Tiling
#define MT       64         // tokens per block
#define BK       64         // K-chunk for h GEMM
#define NTHR     256

// ---------------------------------------------------------------------------
// Kernel A: build paired codebook-output table
// P2[p][i*8+j][o] = sum_d cb[2p][i][d]*W_post[2p*64+d][o]
//                 + sum_d cb[2p+1][j][d]*W_post[(2p+1)*64+d][o]
// stored bf16, 4*64*512 entries = 256 KB in d_ws.
// ---------------------------------------------------------------------------
__global__ __launch_bounds__(128) void build_p2(
    const float* __restrict__ codebook,   // (8,8,64)
    const float* __restrict__ W_post,     // (512,512)
    __hip_bfloat16* __restrict__ P2)
{
    const int b  = blockIdx.x;     // 0..255
    const int p  = b >> 6;         // pair 0..3
    const int ij = b & 63;
    const int i  = ij >> 3, j = ij & 7;
    const int t  = threadIdx.x;    // 0..127

    const float* ca = codebook + ((size_t)(2 * p) * NV + i) * VD;
    const float* cb = codebook + ((size_t)(2 * p + 1) * NV + j) * VD;
    const float* wa = W_post + (size_t)(2 * p) * VD * OUT_DIM;
    const float* wb = W_post + (size_t)(2 * p + 1) * VD * OUT_DIM;

    float acc[4] = {0.f, 0.f, 0.f, 0.f};
    for (int d = 0; d < VD; ++d) {
        const float a  = ca[d];          // uniform -> scalar regs
        const float bb = cb[d];
        const float* ra = wa + (size_t)d * OUT_DIM;
        const float* rb = wb + (size_t)d * OUT_DIM;
#pragma unroll
        for (int q = 0; q < 4; ++q) {
            const int o = t + q * 128;
            acc[q] += a * ra[o] + bb * rb[o];
        }
    }
    __hip_bfloat16* dst = P2 + ((size_t)(p * 64 + ij)) * OUT_DIM;
#pragma unroll
    for (int q = 0; q < 4; ++q)
        dst[t + q * 128] = __float2bfloat16(acc[q]);
}

// ---------------------------------------------------------------------------
// Kernel B: fused  h = x@W_pre + b_pre ; logits = h@W_proj + b_proj ;
//           idx = argmax(logits + gumbel(u)) ; out = b_post + gather(P2)
// One block = 64 tokens, 256 threads.
// ---------------------------------------------------------------------------
__global__ __launch_bounds__(256) void fused_main(
    const float* __restrict__ x,        // (BT,512)
    const float* __restrict__ W_pre,    // (512,32)
    const float* __restrict__ b_pre,    // (32)
    const float* __restrict__ W_proj,   // (32,64)
    const float* __restrict__ b_proj,   // (64)
    const float* __restrict__ u,        // (BT,64)
    const float* __restrict__ b_post,   // (512)
    const __hip_bfloat16* __restrict__ P2, // (4,64,512)
    float* __restrict__ out)            // (BT,512)
{
    __shared__ float Xs[MT][BK + 4];        // pad 68: <=2-way bank alias (free)
    __shared__ float Ws[BK][QDIM];          // W_pre K-chunk, [k][j]
    __shared__ float Wp[QDIM][GV];          // W_proj, [j][c]
    __shared__ float Hs[MT][QDIM + 4];      // pad 36
    __shared__ int   idxs[MT][NG];
    __shared__ int   pidxs[MT][4];

    const int t = threadIdx.x;
    const int tokbase = blockIdx.x * MT;

    // stage W_proj once (2048 contiguous floats = 512 float4)
    {
        const float4* src = (const float4*)W_proj;
        float4* dst = (float4*)&Wp[0][0];
        dst[t]       = src[t];
        dst[t + 256] = src[t + 256];
    }

    // ---------------- Phase 1: h = x @ W_pre + b_pre ----------------
    // thread -> 2 tokens (tm,tm+1) x 4 outputs (n4..n4+3)
    const int n4 = (t & 7) * 4;
    const int tm = (t >> 3) * 2;
    const float4 bp = *(const float4*)&b_pre[n4];
    float acc0[4] = {bp.x, bp.y, bp.z, bp.w};
    float acc1[4] = {bp.x, bp.y, bp.z, bp.w};

    const int xrow = t >> 2;       // 0..63
    const int xq   = t & 3;

    for (int k0 = 0; k0 < IN_DIM; k0 += BK) {
        __syncthreads();
        // stage X tile: 64 rows x 64 floats
        {
            const float4* src =
                (const float4*)(x + (size_t)(tokbase + xrow) * IN_DIM + k0);
#pragma unroll
            for (int uq = 0; uq < 4; ++uq) {
                float4 v = src[xq + 4 * uq];
                *(float4*)&Xs[xrow][4 * (xq + 4 * uq)] = v;
            }
        }
        // stage W_pre chunk: rows k0..k0+63 -> 2048 contiguous floats
        {
            const float4* src = (const float4*)(W_pre + (size_t)k0 * QDIM);
            float4* dst = (float4*)&Ws[0][0];
            dst[t]       = src[t];
            dst[t + 256] = src[t + 256];
        }
        __syncthreads();

#pragma unroll 16
        for (int kk = 0; kk < BK; ++kk) {
            const float a0 = Xs[tm][kk];
            const float a1 = Xs[tm + 1][kk];
            const float4 w = *(const float4*)&Ws[kk][n4];
            acc0[0] += a0 * w.x; acc0[1] += a0 * w.y;
            acc0[2] += a0 * w.z; acc0[3] += a0 * w.w;
            acc1[0] += a1 * w.x; acc1[1] += a1 * w.y;
            acc1[2] += a1 * w.z; acc1[3] += a1 * w.w;
        }
    }

    __syncthreads();
    *(float4*)&Hs[tm][n4]     = make_float4(acc0[0], acc0[1], acc0[2], acc0[3]);
    *(float4*)&Hs[tm + 1][n4] = make_float4(acc1[0], acc1[1], acc1[2], acc1[3]);
    __syncthreads();

    // ---------------- Phase 2: logits + gumbel + argmax ----------------
    // task = (token, group); 512 tasks, 2 per thread
#pragma unroll
    for (int tt = 0; tt < 2; ++tt) {
        const int task = t + tt * 256;
        const int tok  = task >> 3;
        const int g    = task & 7;

        const float4 bj0 = *(const float4*)&b_proj[g * 8];
        const float4 bj1 = *(const float4*)&b_proj[g * 8 + 4];
        float lg[8] = {bj0.x, bj0.y, bj0.z, bj0.w, bj1.x, bj1.y, bj1.z, bj1.w};

#pragma unroll
        for (int j = 0; j < QDIM; ++j) {
            const float hv = Hs[tok][j];
            const float4 w0 = *(const float4*)&Wp[j][g * 8];
            const float4 w1 = *(const float4*)&Wp[j][g * 8 + 4];
            lg[0] += hv * w0.x; lg[1] += hv * w0.y;
            lg[2] += hv * w0.z; lg[3] += hv * w0.w;
            lg[4] += hv * w1.x; lg[5] += hv * w1.y;
            lg[6] += hv * w1.z; lg[7] += hv * w1.w;
        }

        // gumbel: y = logit - log(-log(u+eps)+eps)   (argmax invariant to /tau)
        const float4* up = (const float4*)(u + (size_t)tokbase * GV);
        const float4 u0 = up[task * 2];
        const float4 u1 = up[task * 2 + 1];
        float y[8];
        y[0] = lg[0] - logf(-logf(u0.x + EPS_G) + EPS_G);
        y[1] = lg[1] - logf(-logf(u0.y + EPS_G) + EPS_G);
        y[2] = lg[2] - logf(-logf(u0.z + EPS_G) + EPS_G);
        y[3] = lg[3] - logf(-logf(u0.w + EPS_G) + EPS_G);
        y[4] = lg[4] - logf(-logf(u1.x + EPS_G) + EPS_G);
        y[5] = lg[5] - logf(-logf(u1.y + EPS_G) + EPS_G);
        y[6] = lg[6] - logf(-logf(u1.z + EPS_G) + EPS_G);
        y[7] = lg[7] - logf(-logf(u1.w + EPS_G) + EPS_G);

        float best = y[0];
        int bi = 0;
#pragma unroll
        for (int v = 1; v < 8; ++v) {
            if (y[v] > best) { best = y[v]; bi = v; }  // strict > == np first-max
        }
        idxs[tok][g] = bi;
    }
    __syncthreads();

    // pair indices: pidx = idx[2p]*8 + idx[2p+1]
    {
        const int tok = t >> 2, p = t & 3;
        pidxs[tok][p] = idxs[tok][2 * p] * 8 + idxs[tok][2 * p + 1];
    }
    __syncthreads();

    // ---------------- Phase 3: out = b_post + sum_p P2[p][pidx] ----------------
    const int o2 = t * 2;
    const float b0 = b_post[o2];
    const float b1 = b_post[o2 + 1];
    float* outp = out + (size_t)tokbase * OUT_DIM;
    const uint16_t* p2u = (const uint16_t*)P2;

#pragma unroll 4
    for (int tok = 0; tok < MT; ++tok) {
        float r0 = b0, r1 = b1;
#pragma unroll
        for (int p = 0; p < 4; ++p) {
            const int pi = pidxs[tok][p];
            const uint32_t raw =
                *(const uint32_t*)(p2u + ((size_t)(p * 64 + pi) * OUT_DIM + o2));
            r0 += __uint_as_float(raw << 16);          // bf16 -> f32
            r1 += __uint_as_float(raw & 0xffff0000u);
        }
        *(float2*)&outp[(size_t)tok * OUT_DIM + o2] = make_float2(r0, r1);
    }
}

// ---------------------------------------------------------------------------
extern "C" void kernel_launch(void* const* d_in, const int* in_sizes, int n_in,
                              void* d_out, int out_size, void* d_ws, size_t ws_size,
                              hipStream_t stream) {
    const float* x        = (const float*)d_in[0];
    const float* W_pre    = (const float*)d_in[1];
    const float* b_pre    = (const float*)d_in[2];
    const float* W_proj   = (const float*)d_in[3];
    const float* b_proj   = (const float*)d_in[4];
    const float* codebook = (const float*)d_in[5];
    const float* W_post   = (const float*)d_in[6];
    const float* b_post   = (const float*)d_in[7];
    const float* u        = (const float*)d_in[8];
    float* out = (float*)d_out;

    __hip_bfloat16* P2 = (__hip_bfloat16*)d_ws;   // 256 KB

    build_p2<<<256, 128, 0, stream>>>(codebook, W_post, P2);
    fused_main<<<BT_TOK / MT, NTHR, 0, stream>>>(x, W_pre, b_pre, W_proj, b_proj,
                                                 u, b_post, P2, out);
}

// Round 2
// 169.599 us; speedup vs baseline: 1.0924x; 1.0924x over previous
//
#include <hip/hip_runtime.h>
#include <hip/hip_bf16.h>
#include <stdint.h>
#include <stddef.h>

// Problem constants
#define BT_TOK   32768      // B*T
#define IN_DIM   512
#define OUT_DIM  512
#define QDIM     32
#define NG       8
#define NV       8
#define VD       64
#define EPS_G    1e-10f

#define MT       64         // tokens per block (= lanes per wave)

// ---------------------------------------------------------------------------
// Kernel A: paired codebook-output table
// P2[p][i*8+j][o] = cb[2p][i]@W_post[2p*64:...] + cb[2p+1][j]@W_post[...]
// bf16, 4*64*512 = 256 KB in d_ws. Rebuilt every call (ws is re-poisoned).
// ---------------------------------------------------------------------------
__global__ __launch_bounds__(256) void build_p2(
    const float* __restrict__ codebook,   // (8,8,64)
    const float* __restrict__ W_post,     // (512,512)
    __hip_bfloat16* __restrict__ P2)
{
    const int b  = blockIdx.x;     // 0..255
    const int p  = b >> 6;         // pair 0..3
    const int ij = b & 63;
    const int i  = ij >> 3, j = ij & 7;
    const int t  = threadIdx.x;    // 0..255

    const float* ca  = codebook + ((size_t)(2 * p) * NV + i) * VD;
    const float* cbp = codebook + ((size_t)(2 * p + 1) * NV + j) * VD;
    const float* wa  = W_post + (size_t)(2 * p) * VD * OUT_DIM;
    const float* wb  = W_post + (size_t)(2 * p + 1) * VD * OUT_DIM;

    float a0 = 0.f, a1 = 0.f;
#pragma unroll 8
    for (int d = 0; d < VD; ++d) {
        const float sa = ca[d];            // block-uniform -> scalar
        const float sb = cbp[d];
        a0 += sa * wa[(size_t)d * OUT_DIM + t]       + sb * wb[(size_t)d * OUT_DIM + t];
        a1 += sa * wa[(size_t)d * OUT_DIM + t + 256] + sb * wb[(size_t)d * OUT_DIM + t + 256];
    }
    __hip_bfloat16* dst = P2 + ((size_t)(p * 64 + ij)) * OUT_DIM;
    dst[t]       = __float2bfloat16(a0);
    dst[t + 256] = __float2bfloat16(a1);
}

// ---------------------------------------------------------------------------
// Kernel B: fused  h = x@W_pre+b_pre ; logits = h@W_proj+b_proj ;
//           idx = argmax(logits+gumbel(u)) ; out = b_post + gather(P2)
// Block: 256 threads = 4 waves, 64 tokens. lane = token; wave = K-quarter.
// W operands are wave-uniform -> scalar loads; x read direct from global
// (each lane's 32-float chunk = one aligned 128B line, L1-reused).
// ---------------------------------------------------------------------------
__global__ __launch_bounds__(256, 3) void fused_main(
    const float* __restrict__ x,        // (BT,512)
    const float* __restrict__ W_pre,    // (512,32)
    const float* __restrict__ b_pre,    // (32)
    const float* __restrict__ W_proj,   // (32,64)
    const float* __restrict__ b_proj,   // (64)
    const float* __restrict__ u,        // (BT,64)
    const float* __restrict__ b_post,   // (512)
    const __hip_bfloat16* __restrict__ P2, // (4,64,512)
    float* __restrict__ out)            // (BT,512)
{
    __shared__ float Hs4[4][MT][36];    // partial h per K-quarter (36: b128-aligned pad)
    __shared__ int   pidx_s[4][MT];     // paired codebook index per token

    const int t    = threadIdx.x;
    const int lane = t & 63;                                   // token within block
    const int w    = __builtin_amdgcn_readfirstlane(t >> 6);   // wave id = K-quarter / pair
    const int tokbase = blockIdx.x * MT;
    const int gtok    = tokbase + lane;

    // ---------------- Phase 1: partial h over K-quarter [w*128, w*128+128) ----
    float acc[QDIM];
#pragma unroll
    for (int j = 0; j < QDIM; ++j) acc[j] = 0.f;

    const float* xrow = x + (size_t)gtok * IN_DIM + w * 128;

    for (int c = 0; c < 4; ++c) {                 // 4 chunks of 32 k
        float4 xr[8];
#pragma unroll
        for (int f = 0; f < 8; ++f)
            xr[f] = ((const float4*)xrow)[c * 8 + f];   // one 128B line, L1-hot

        const float* wbase = W_pre + (size_t)(w * 128 + c * 32) * QDIM;
#pragma unroll
        for (int kk = 0; kk < 32; ++kk) {
            const float xv = ((const float*)xr)[kk];
            const float4* wr = (const float4*)(wbase + (size_t)kk * QDIM); // uniform
            const float4 w0 = wr[0], w1 = wr[1], w2 = wr[2], w3 = wr[3];
            const float4 w4 = wr[4], w5 = wr[5], w6 = wr[6], w7 = wr[7];
            acc[0]  += xv * w0.x; acc[1]  += xv * w0.y; acc[2]  += xv * w0.z; acc[3]  += xv * w0.w;
            acc[4]  += xv * w1.x; acc[5]  += xv * w1.y; acc[6]  += xv * w1.z; acc[7]  += xv * w1.w;
            acc[8]  += xv * w2.x; acc[9]  += xv * w2.y; acc[10] += xv * w2.z; acc[11] += xv * w2.w;
            acc[12] += xv * w3.x; acc[13] += xv * w3.y; acc[14] += xv * w3.z; acc[15] += xv * w3.w;
            acc[16] += xv * w4.x; acc[17] += xv * w4.y; acc[18] += xv * w4.z; acc[19] += xv * w4.w;
            acc[20] += xv * w5.x; acc[21] += xv * w5.y; acc[22] += xv * w5.z; acc[23] += xv * w5.w;
            acc[24] += xv * w6.x; acc[25] += xv * w6.y; acc[26] += xv * w6.z; acc[27] += xv * w6.w;
            acc[28] += xv * w7.x; acc[29] += xv * w7.y; acc[30] += xv * w7.z; acc[31] += xv * w7.w;
        }
    }

    // write partials (b128, conflict-free: stride 36 floats -> 16B-group = lane mod 8)
#pragma unroll
    for (int j4 = 0; j4 < 8; ++j4)
        *(float4*)&Hs4[w][lane][j4 * 4] =
            make_float4(acc[j4 * 4], acc[j4 * 4 + 1], acc[j4 * 4 + 2], acc[j4 * 4 + 3]);
    __syncthreads();

    // reduce 4 K-quarters in place (each cell owned by exactly one thread)
#pragma unroll
    for (int r = 0; r < 8; ++r) {
        const int id  = t + 256 * r;          // 2048 (tok,j) cells
        const int tok = id >> 5;
        const int j   = id & 31;
        const float h = b_pre[j] + Hs4[0][tok][j] + Hs4[1][tok][j]
                                 + Hs4[2][tok][j] + Hs4[3][tok][j];
        Hs4[0][tok][j] = h;
    }
    __syncthreads();

    // ---------------- Phase 2: logits + gumbel + argmax (wave w -> groups 2w,2w+1)
    float h[QDIM];
#pragma unroll
    for (int j4 = 0; j4 < 8; ++j4) {
        const float4 v = *(const float4*)&Hs4[0][lane][j4 * 4];
        h[j4 * 4] = v.x; h[j4 * 4 + 1] = v.y; h[j4 * 4 + 2] = v.z; h[j4 * 4 + 3] = v.w;
    }

    int idx2[2];
#pragma unroll
    for (int gg = 0; gg < 2; ++gg) {
        const int g = 2 * w + gg;                       // wave-uniform
        const float4 b0 = *(const float4*)&b_proj[g * 8];
        const float4 b1 = *(const float4*)&b_proj[g * 8 + 4];
        float lg[8] = {b0.x, b0.y, b0.z, b0.w, b1.x, b1.y, b1.z, b1.w};

#pragma unroll
        for (int j = 0; j < QDIM; ++j) {
            const float hv = h[j];
            const float4 a0 = *(const float4*)&W_proj[(size_t)j * 64 + g * 8];     // uniform
            const float4 a1 = *(const float4*)&W_proj[(size_t)j * 64 + g * 8 + 4]; // uniform
            lg[0] += hv * a0.x; lg[1] += hv * a0.y; lg[2] += hv * a0.z; lg[3] += hv * a0.w;
            lg[4] += hv * a1.x; lg[5] += hv * a1.y; lg[6] += hv * a1.z; lg[7] += hv * a1.w;
        }

        const float4 u0 = *(const float4*)&u[(size_t)gtok * 64 + g * 8];
        const float4 u1 = *(const float4*)&u[(size_t)gtok * 64 + g * 8 + 4];
        float y[8];
        y[0] = lg[0] - logf(-logf(u0.x + EPS_G) + EPS_G);
        y[1] = lg[1] - logf(-logf(u0.y + EPS_G) + EPS_G);
        y[2] = lg[2] - logf(-logf(u0.z + EPS_G) + EPS_G);
        y[3] = lg[3] - logf(-logf(u0.w + EPS_G) + EPS_G);
        y[4] = lg[4] - logf(-logf(u1.x + EPS_G) + EPS_G);
        y[5] = lg[5] - logf(-logf(u1.y + EPS_G) + EPS_G);
        y[6] = lg[6] - logf(-logf(u1.z + EPS_G) + EPS_G);
        y[7] = lg[7] - logf(-logf(u1.w + EPS_G) + EPS_G);

        float best = y[0];
        int bi = 0;
#pragma unroll
        for (int v = 1; v < 8; ++v)
            if (y[v] > best) { best = y[v]; bi = v; }   // strict > == np first-max
        idx2[gg] = bi;
    }
    pidx_s[w][lane] = idx2[0] * 8 + idx2[1];   // wave w == pair p
    __syncthreads();

    // ---------------- Phase 3: out = b_post + sum_p P2[p][pidx] ----------------
    const int o2 = t * 2;
    const float bp0 = b_post[o2];
    const float bp1 = b_post[o2 + 1];
    float* orow = out + (size_t)tokbase * OUT_DIM;
    const uint32_t* p2u = (const uint32_t*)P2;   // 2 bf16 per uint32

#pragma unroll 4
    for (int tok = 0; tok < MT; ++tok) {
        const int p0 = pidx_s[0][tok];
        const int p1 = pidx_s[1][tok];
        const int p2i = pidx_s[2][tok];
        const int p3 = pidx_s[3][tok];
        const uint32_t r0 = p2u[(size_t)(0 * 64 + p0) * 256 + t];
        const uint32_t r1 = p2u[(size_t)(1 * 64 + p1) * 256 + t];
        const uint32_t r2 = p2u[(size_t)(2 * 64 + p2i) * 256 + t];
        const uint32_t r3 = p2u[(size_t)(3 * 64 + p3) * 256 + t];
        float s0 = bp0, s1 = bp1;
        s0 += __uint_as_float(r0 << 16); s1 += __uint_as_float(r0 & 0xffff0000u);
        s0 += __uint_as_float(r1 << 16); s1 += __uint_as_float(r1 & 0xffff0000u);
        s0 += __uint_as_float(r2 << 16); s1 += __uint_as_float(r2 & 0xffff0000u);
        s0 += __uint_as_float(r3 << 16); s1 += __uint_as_float(r3 & 0xffff0000u);
        *(float2*)&orow[(size_t)tok * OUT_DIM + o2] = make_float2(s0, s1);
    }
}

// ---------------------------------------------------------------------------
extern "C" void kernel_launch(void* const* d_in, const int* in_sizes, int n_in,
                              void* d_out, int out_size, void* d_ws, size_t ws_size,
                              hipStream_t stream) {
    const float* x        = (const float*)d_in[0];
    const float* W_pre    = (const float*)d_in[1];
    const float* b_pre    = (const float*)d_in[2];
    const float* W_proj   = (const float*)d_in[3];
    const float* b_proj   = (const float*)d_in[4];
    const float* codebook = (const float*)d_in[5];
    const float* W_post   = (const float*)d_in[6];
    const float* b_post   = (const float*)d_in[7];
    const float* u        = (const float*)d_in[8];
    float* out = (float*)d_out;

    __hip_bfloat16* P2 = (__hip_bfloat16*)d_ws;   // 256 KB

    build_p2<<<256, 256, 0, stream>>>(codebook, W_post, P2);
    fused_main<<<BT_TOK / MT, 256, 0, stream>>>(x, W_pre, b_pre, W_proj, b_proj,
                                                u, b_post, P2, out);
}

// Round 3
// 159.912 us; speedup vs baseline: 1.1586x; 1.0606x over previous
//
#include <hip/hip_runtime.h>
#include <hip/hip_bf16.h>
#include <stdint.h>
#include <stddef.h>

// Problem constants
#define BT_TOK   32768      // B*T
#define IN_DIM   512
#define OUT_DIM  512
#define QDIM     32
#define NG       8
#define NV       8
#define VD       64
#define EPS_G    1e-10f

#define MT       64         // tokens per block (= lanes per wave)
#define NW       8          // waves per block = K-split factor

// ---------------------------------------------------------------------------
// Kernel A: paired codebook-output table
// P2[p][i*8+j][o] = cb[2p][i]@W_post[2p*64:...] + cb[2p+1][j]@W_post[...]
// bf16, 4*64*512 = 256 KB in d_ws. Rebuilt every call (ws is re-poisoned).
// ---------------------------------------------------------------------------
__global__ __launch_bounds__(256) void build_p2(
    const float* __restrict__ codebook,   // (8,8,64)
    const float* __restrict__ W_post,     // (512,512)
    __hip_bfloat16* __restrict__ P2)
{
    const int b  = blockIdx.x;     // 0..255
    const int p  = b >> 6;         // pair 0..3
    const int ij = b & 63;
    const int i  = ij >> 3, j = ij & 7;
    const int t  = threadIdx.x;    // 0..255

    const float* ca  = codebook + ((size_t)(2 * p) * NV + i) * VD;
    const float* cbp = codebook + ((size_t)(2 * p + 1) * NV + j) * VD;
    const float* wa  = W_post + (size_t)(2 * p) * VD * OUT_DIM;
    const float* wb  = W_post + (size_t)(2 * p + 1) * VD * OUT_DIM;

    float a0 = 0.f, a1 = 0.f;
#pragma unroll 8
    for (int d = 0; d < VD; ++d) {
        const float sa = ca[d];            // block-uniform -> scalar
        const float sb = cbp[d];
        a0 += sa * wa[(size_t)d * OUT_DIM + t]       + sb * wb[(size_t)d * OUT_DIM + t];
        a1 += sa * wa[(size_t)d * OUT_DIM + t + 256] + sb * wb[(size_t)d * OUT_DIM + t + 256];
    }
    __hip_bfloat16* dst = P2 + ((size_t)(p * 64 + ij)) * OUT_DIM;
    dst[t]       = __float2bfloat16(a0);
    dst[t + 256] = __float2bfloat16(a1);
}

// ---------------------------------------------------------------------------
// Kernel B: fused  h = x@W_pre+b_pre ; logits = h@W_proj+b_proj ;
//           idx = argmax(logits+gumbel(u)) ; out = b_post + gather(P2)
// Block: 512 threads = 8 waves, 64 tokens. lane = token; wave = K-eighth.
// 2 blocks/CU (LDS 75KB) -> 16 waves/CU, double round-2 residency.
// W operands wave-uniform -> scalar loads; x read direct from global.
// ---------------------------------------------------------------------------
__global__ __launch_bounds__(512, 4) void fused_main(
    const float* __restrict__ x,        // (BT,512)
    const float* __restrict__ W_pre,    // (512,32)
    const float* __restrict__ b_pre,    // (32)
    const float* __restrict__ W_proj,   // (32,64)
    const float* __restrict__ b_proj,   // (64)
    const float* __restrict__ u,        // (BT,64)
    const float* __restrict__ b_post,   // (512)
    const __hip_bfloat16* __restrict__ P2, // (4,64,512)
    float* __restrict__ out)            // (BT,512)
{
    __shared__ float Hs4[NW][MT][36];   // partial h per K-eighth (stride 36: 0 conflicts, measured)
    __shared__ int   idxs_s[NG][MT];    // argmax per (group, token)
    __shared__ int   pidx_s[4][MT];     // paired codebook index per token

    const int t    = threadIdx.x;
    const int lane = t & 63;                                   // token within block
    const int w    = __builtin_amdgcn_readfirstlane(t >> 6);   // wave id = K-eighth / group
    const int tokbase = blockIdx.x * MT;
    const int gtok    = tokbase + lane;

    // ---------------- Phase 1: partial h over K-slice [w*64, w*64+64) --------
    float acc[QDIM];
#pragma unroll
    for (int j = 0; j < QDIM; ++j) acc[j] = 0.f;

    const float* xrow = x + (size_t)gtok * IN_DIM + w * 64;

#pragma unroll
    for (int c = 0; c < 2; ++c) {                 // 2 chunks of 32 k
        float4 xr[8];
#pragma unroll
        for (int f = 0; f < 8; ++f)
            xr[f] = ((const float4*)xrow)[c * 8 + f];   // one 128B line/lane

        const float* wbase = W_pre + (size_t)(w * 64 + c * 32) * QDIM;
#pragma unroll
        for (int kk = 0; kk < 32; ++kk) {
            const float xv = ((const float*)xr)[kk];
            const float4* wr = (const float4*)(wbase + (size_t)kk * QDIM); // uniform
            const float4 w0 = wr[0], w1 = wr[1], w2 = wr[2], w3 = wr[3];
            const float4 w4 = wr[4], w5 = wr[5], w6 = wr[6], w7 = wr[7];
            acc[0]  += xv * w0.x; acc[1]  += xv * w0.y; acc[2]  += xv * w0.z; acc[3]  += xv * w0.w;
            acc[4]  += xv * w1.x; acc[5]  += xv * w1.y; acc[6]  += xv * w1.z; acc[7]  += xv * w1.w;
            acc[8]  += xv * w2.x; acc[9]  += xv * w2.y; acc[10] += xv * w2.z; acc[11] += xv * w2.w;
            acc[12] += xv * w3.x; acc[13] += xv * w3.y; acc[14] += xv * w3.z; acc[15] += xv * w3.w;
            acc[16] += xv * w4.x; acc[17] += xv * w4.y; acc[18] += xv * w4.z; acc[19] += xv * w4.w;
            acc[20] += xv * w5.x; acc[21] += xv * w5.y; acc[22] += xv * w5.z; acc[23] += xv * w5.w;
            acc[24] += xv * w6.x; acc[25] += xv * w6.y; acc[26] += xv * w6.z; acc[27] += xv * w6.w;
            acc[28] += xv * w7.x; acc[29] += xv * w7.y; acc[30] += xv * w7.z; acc[31] += xv * w7.w;
        }
    }

    // write partials (b128; stride-36 layout measured conflict-free)
#pragma unroll
    for (int j4 = 0; j4 < 8; ++j4)
        *(float4*)&Hs4[w][lane][j4 * 4] =
            make_float4(acc[j4 * 4], acc[j4 * 4 + 1], acc[j4 * 4 + 2], acc[j4 * 4 + 3]);
    __syncthreads();

    // reduce 8 K-slices in place (each cell owned by exactly one thread)
#pragma unroll
    for (int r = 0; r < 4; ++r) {
        const int id  = t + 512 * r;          // 2048 (tok,j) cells
        const int tok = id >> 5;
        const int j   = id & 31;
        float h = b_pre[j];
#pragma unroll
        for (int q = 0; q < NW; ++q) h += Hs4[q][tok][j];
        Hs4[0][tok][j] = h;
    }
    __syncthreads();

    // ---------------- Phase 2: logits + gumbel + argmax (wave w -> group w) ---
    float h[QDIM];
#pragma unroll
    for (int j4 = 0; j4 < 8; ++j4) {
        const float4 v = *(const float4*)&Hs4[0][lane][j4 * 4];
        h[j4 * 4] = v.x; h[j4 * 4 + 1] = v.y; h[j4 * 4 + 2] = v.z; h[j4 * 4 + 3] = v.w;
    }

    {
        const int g = w;                                // wave-uniform group
        const float4 b0 = *(const float4*)&b_proj[g * 8];
        const float4 b1 = *(const float4*)&b_proj[g * 8 + 4];
        float lg[8] = {b0.x, b0.y, b0.z, b0.w, b1.x, b1.y, b1.z, b1.w};

#pragma unroll
        for (int j = 0; j < QDIM; ++j) {
            const float hv = h[j];
            const float4 a0 = *(const float4*)&W_proj[(size_t)j * 64 + g * 8];     // uniform
            const float4 a1 = *(const float4*)&W_proj[(size_t)j * 64 + g * 8 + 4]; // uniform
            lg[0] += hv * a0.x; lg[1] += hv * a0.y; lg[2] += hv * a0.z; lg[3] += hv * a0.w;
            lg[4] += hv * a1.x; lg[5] += hv * a1.y; lg[6] += hv * a1.z; lg[7] += hv * a1.w;
        }

        const float4 u0 = *(const float4*)&u[(size_t)gtok * 64 + g * 8];
        const float4 u1 = *(const float4*)&u[(size_t)gtok * 64 + g * 8 + 4];
        float y[8];
        y[0] = lg[0] - logf(-logf(u0.x + EPS_G) + EPS_G);
        y[1] = lg[1] - logf(-logf(u0.y + EPS_G) + EPS_G);
        y[2] = lg[2] - logf(-logf(u0.z + EPS_G) + EPS_G);
        y[3] = lg[3] - logf(-logf(u0.w + EPS_G) + EPS_G);
        y[4] = lg[4] - logf(-logf(u1.x + EPS_G) + EPS_G);
        y[5] = lg[5] - logf(-logf(u1.y + EPS_G) + EPS_G);
        y[6] = lg[6] - logf(-logf(u1.z + EPS_G) + EPS_G);
        y[7] = lg[7] - logf(-logf(u1.w + EPS_G) + EPS_G);

        float best = y[0];
        int bi = 0;
#pragma unroll
        for (int v = 1; v < 8; ++v)
            if (y[v] > best) { best = y[v]; bi = v; }   // strict > == np first-max
        idxs_s[g][lane] = bi;
    }
    __syncthreads();

    // pair indices: pidx[p][tok] = idx[2p]*8 + idx[2p+1]
    if (t < 256) {
        const int p = t >> 6, tok = t & 63;
        pidx_s[p][tok] = idxs_s[2 * p][tok] * 8 + idxs_s[2 * p + 1][tok];
    }
    __syncthreads();

    // ---------------- Phase 3: out = b_post + sum_p P2[p][pidx] ----------------
    const int tokhalf = t >> 8;          // 0/1 -> tokens [32*tokhalf, +32)
    const int tt = t & 255;
    const int o2 = tt * 2;
    const float bp0 = b_post[o2];
    const float bp1 = b_post[o2 + 1];
    float* orow = out + (size_t)(tokbase + tokhalf * 32) * OUT_DIM;
    const uint32_t* p2u = (const uint32_t*)P2;   // 2 bf16 per uint32

#pragma unroll 4
    for (int tok0 = 0; tok0 < 32; ++tok0) {
        const int tok = tokhalf * 32 + tok0;
        const int p0 = pidx_s[0][tok];
        const int p1 = pidx_s[1][tok];
        const int p2i = pidx_s[2][tok];
        const int p3 = pidx_s[3][tok];
        const uint32_t r0 = p2u[(size_t)(0 * 64 + p0) * 256 + tt];
        const uint32_t r1 = p2u[(size_t)(1 * 64 + p1) * 256 + tt];
        const uint32_t r2 = p2u[(size_t)(2 * 64 + p2i) * 256 + tt];
        const uint32_t r3 = p2u[(size_t)(3 * 64 + p3) * 256 + tt];
        float s0 = bp0, s1 = bp1;
        s0 += __uint_as_float(r0 << 16); s1 += __uint_as_float(r0 & 0xffff0000u);
        s0 += __uint_as_float(r1 << 16); s1 += __uint_as_float(r1 & 0xffff0000u);
        s0 += __uint_as_float(r2 << 16); s1 += __uint_as_float(r2 & 0xffff0000u);
        s0 += __uint_as_float(r3 << 16); s1 += __uint_as_float(r3 & 0xffff0000u);
        *(float2*)&orow[(size_t)tok0 * OUT_DIM + o2] = make_float2(s0, s1);
    }
}

// ---------------------------------------------------------------------------
extern "C" void kernel_launch(void* const* d_in, const int* in_sizes, int n_in,
                              void* d_out, int out_size, void* d_ws, size_t ws_size,
                              hipStream_t stream) {
    const float* x        = (const float*)d_in[0];
    const float* W_pre    = (const float*)d_in[1];
    const float* b_pre    = (const float*)d_in[2];
    const float* W_proj   = (const float*)d_in[3];
    const float* b_proj   = (const float*)d_in[4];
    const float* codebook = (const float*)d_in[5];
    const float* W_post   = (const float*)d_in[6];
    const float* b_post   = (const float*)d_in[7];
    const float* u        = (const float*)d_in[8];
    float* out = (float*)d_out;

    __hip_bfloat16* P2 = (__hip_bfloat16*)d_ws;   // 256 KB

    build_p2<<<256, 256, 0, stream>>>(codebook, W_post, P2);
    fused_main<<<BT_TOK / MT, 512, 0, stream>>>(x, W_pre, b_pre, W_proj, b_proj,
                                                u, b_post, P2, out);
}